// Round 12
// baseline (13854.077 us; speedup 1.0000x reference)
//
#include <hip/hip_runtime.h>
#include <math.h>

#define NMOD 4
#define BB   8
#define NN   4096
#define MM   4608
#define TPB  256
#define NSET 3                      // target sets: mod0-noise, mod1-noise, clean
#define NG   (NSET * BB)            // 24 grids
#define GC   24                     // cells per dimension
#define NCELL (GC * GC * GC)        // 13824
#define QCOUNT (NMOD * BB * NN)     // 131072
#define NXBLK2 (NN / TPB)           // 16
#define NPART  (NMOD * BB * NXBLK2) // 512

// ---- workspace layout (compile-time, 256B aligned) ----
#define SZ_GOFF  ((size_t)NG * (NCELL + 1) * 4)
#define OFF_GT   ((SZ_GOFF + 255) & ~(size_t)255)
#define SZ_GT    ((size_t)NG * MM * 16)
#define OFF_GI   ((OFF_GT + SZ_GT + 255) & ~(size_t)255)
#define SZ_GI    ((size_t)NG * MM * 4)
#define OFF_GBOX ((OFF_GI + SZ_GI + 255) & ~(size_t)255)
#define SZ_GBOX  ((size_t)NG * 8 * 4)
#define OFF_KEYS ((OFF_GBOX + SZ_GBOX + 255) & ~(size_t)255)
#define SZ_KEYS  ((size_t)QCOUNT * 8)
#define OFF_PART ((OFF_KEYS + SZ_KEYS + 255) & ~(size_t)255)
#define WS_NEED  (OFF_PART + (size_t)NPART * 4)

static __device__ __forceinline__ int clampi(int v, int lo, int hi) {
    return v < lo ? lo : (v > hi ? hi : v);
}

// target coordinates, identical formula everywhere (build, pass2)
#define TGT_XYZ(SET, B, M, TX, TY, TZ) do {                               \
        const size_t oc_ = ((size_t)(B) * MM + (M)) * 3;                  \
        TX = clean[oc_ + 0] - sx;                                         \
        TY = clean[oc_ + 1] - sy;                                         \
        TZ = clean[oc_ + 2] - sz;                                         \
        if ((SET) < 2) {                                                  \
            const size_t on_ = (((size_t)(SET) * BB + (B)) * MM + (M)) * 3;\
            TX = fmaf(noise[on_ + 0], nstd, TX);                          \
            TY = fmaf(noise[on_ + 1], nstd, TY);                          \
            TZ = fmaf(noise[on_ + 2], nstd, TZ);                          \
        }                                                                 \
    } while (0)

// ---------------- grid build: one block per (set,b) grid --------------------
__global__ __launch_bounds__(TPB) void build_kernel(
    const float* __restrict__ clean, const float* __restrict__ seeds,
    const float* __restrict__ stds,  const float* __restrict__ noise,
    unsigned* __restrict__ gOff, float4* __restrict__ gT,
    unsigned* __restrict__ gI,   float* __restrict__ gBox)
{
    __shared__ unsigned cnt[NCELL];      // 55296 B
    __shared__ unsigned part[TPB];
    __shared__ float sb[4][6];
    __shared__ float boxl[8];

    const int g   = blockIdx.x;
    const int set = g / BB;
    const int b   = g % BB;
    const int tid = threadIdx.x;

    const float sx = seeds[b * 3 + 0];
    const float sy = seeds[b * 3 + 1];
    const float sz = seeds[b * 3 + 2];
    float nstd = 0.0f;
    if (set == 0) nstd = stds[b] * 0.25f;
    else if (set == 1) nstd = stds[b] * 0.0625f;

    // --- phase 1: bounding box ---
    float mnx = INFINITY, mny = INFINITY, mnz = INFINITY;
    float mxx = -INFINITY, mxy = -INFINITY, mxz = -INFINITY;
    for (int m = tid; m < MM; m += TPB) {
        float tx, ty, tz; TGT_XYZ(set, b, m, tx, ty, tz);
        mnx = fminf(mnx, tx); mny = fminf(mny, ty); mnz = fminf(mnz, tz);
        mxx = fmaxf(mxx, tx); mxy = fmaxf(mxy, ty); mxz = fmaxf(mxz, tz);
    }
    for (int o = 32; o; o >>= 1) {
        mnx = fminf(mnx, __shfl_down(mnx, o));
        mny = fminf(mny, __shfl_down(mny, o));
        mnz = fminf(mnz, __shfl_down(mnz, o));
        mxx = fmaxf(mxx, __shfl_down(mxx, o));
        mxy = fmaxf(mxy, __shfl_down(mxy, o));
        mxz = fmaxf(mxz, __shfl_down(mxz, o));
    }
    if ((tid & 63) == 0) {
        const int w = tid >> 6;
        sb[w][0] = mnx; sb[w][1] = mny; sb[w][2] = mnz;
        sb[w][3] = mxx; sb[w][4] = mxy; sb[w][5] = mxz;
    }
    __syncthreads();
    if (tid == 0) {
        float n0 = fminf(fminf(sb[0][0], sb[1][0]), fminf(sb[2][0], sb[3][0]));
        float n1 = fminf(fminf(sb[0][1], sb[1][1]), fminf(sb[2][1], sb[3][1]));
        float n2 = fminf(fminf(sb[0][2], sb[1][2]), fminf(sb[2][2], sb[3][2]));
        float x0 = fmaxf(fmaxf(sb[0][3], sb[1][3]), fmaxf(sb[2][3], sb[3][3]));
        float x1 = fmaxf(fmaxf(sb[0][4], sb[1][4]), fmaxf(sb[2][4], sb[3][4]));
        float x2 = fmaxf(fmaxf(sb[0][5], sb[1][5]), fmaxf(sb[2][5], sb[3][5]));
        const float e0 = x0 - n0 + 1e-5f, e1 = x1 - n1 + 1e-5f, e2 = x2 - n2 + 1e-5f;
        boxl[0] = n0; boxl[1] = n1; boxl[2] = n2;
        boxl[3] = (float)GC / e0; boxl[4] = (float)GC / e1; boxl[5] = (float)GC / e2;
        boxl[6] = fminf(e0 / GC, fminf(e1 / GC, e2 / GC));   // hmin
        boxl[7] = 0.0f;
        for (int i = 0; i < 8; ++i) gBox[g * 8 + i] = boxl[i];
    }
    __syncthreads();
    const float bx = boxl[0], by = boxl[1], bz = boxl[2];
    const float s0 = boxl[3], s1 = boxl[4], s2 = boxl[5];

    // --- phase 2: zero counts ---
    for (int c = tid; c < NCELL; c += TPB) cnt[c] = 0;
    __syncthreads();

    // --- phase 3: count ---
    for (int m = tid; m < MM; m += TPB) {
        float tx, ty, tz; TGT_XYZ(set, b, m, tx, ty, tz);
        const int cx = clampi((int)floorf((tx - bx) * s0), 0, GC - 1);
        const int cy = clampi((int)floorf((ty - by) * s1), 0, GC - 1);
        const int cz = clampi((int)floorf((tz - bz) * s2), 0, GC - 1);
        atomicAdd(&cnt[(cz * GC + cy) * GC + cx], 1u);
    }
    __syncthreads();

    // --- phase 4: exclusive scan (cnt -> starts), write gOff ---
    constexpr int CPT = NCELL / TPB;   // 54
    {
        const int base = tid * CPT;
        unsigned s = 0;
        for (int i = 0; i < CPT; ++i) s += cnt[base + i];
        part[tid] = s;
    }
    __syncthreads();
    if (tid == 0) {
        unsigned r = 0;
        for (int i = 0; i < TPB; ++i) { const unsigned t = part[i]; part[i] = r; r += t; }
    }
    __syncthreads();
    {
        const int base = tid * CPT;
        unsigned r = part[tid];
        unsigned* go = gOff + (size_t)g * (NCELL + 1);
        for (int i = 0; i < CPT; ++i) {
            const unsigned t = cnt[base + i];
            cnt[base + i] = r;          // becomes the scatter cursor
            go[base + i]  = r;
            r += t;
        }
        if (tid == 0) go[NCELL] = MM;
    }
    __syncthreads();

    // --- phase 5: scatter ---
    float4*   gt = gT + (size_t)g * MM;
    unsigned* gi = gI + (size_t)g * MM;
    for (int m = tid; m < MM; m += TPB) {
        float tx, ty, tz; TGT_XYZ(set, b, m, tx, ty, tz);
        const float tw = fmaf(tx, tx, fmaf(ty, ty, tz * tz));
        const int cx = clampi((int)floorf((tx - bx) * s0), 0, GC - 1);
        const int cy = clampi((int)floorf((ty - by) * s1), 0, GC - 1);
        const int cz = clampi((int)floorf((tz - bz) * s2), 0, GC - 1);
        const unsigned pos = atomicAdd(&cnt[(cz * GC + cy) * GC + cx], 1u);
        gt[pos] = make_float4(tx, ty, tz, tw);
        gi[pos] = (unsigned)m;
    }
}

// ---------------- query: exact ring-bounded NN ------------------------------
__global__ __launch_bounds__(TPB, 4) void query_kernel(
    const float* __restrict__ noisy, const float* __restrict__ seeds,
    const float* __restrict__ disp,
    const unsigned* __restrict__ gOff, const float4* __restrict__ gT,
    const unsigned* __restrict__ gI,   const float* __restrict__ gBox,
    unsigned long long* __restrict__ keys)
{
    const int tid = threadIdx.x;
    const int b   = blockIdx.y;
    const int mod = blockIdx.z;
    const int n   = blockIdx.x * TPB + tid;
    const int set = (mod < 2) ? mod : 2;
    const int g   = set * BB + b;

    const float sx = seeds[b * 3 + 0];
    const float sy = seeds[b * 3 + 1];
    const float sz = seeds[b * 3 + 2];

    float qx = noisy[((size_t)b * NN + n) * 3 + 0] - sx;
    float qy = noisy[((size_t)b * NN + n) * 3 + 1] - sy;
    float qz = noisy[((size_t)b * NN + n) * 3 + 2] - sz;
    for (int j = 0; j < mod; ++j) {
        const size_t o = (((size_t)j * BB + b) * NN + n) * 3;
        qx += disp[o + 0]; qy += disp[o + 1]; qz += disp[o + 2];
    }
    const float q2  = fmaf(qx, qx, fmaf(qy, qy, qz * qz));
    const float q28 = q2 + 8.0f;
    const float m2x = -2.0f * qx, m2y = -2.0f * qy, m2z = -2.0f * qz;

    const float* bp = gBox + g * 8;
    const float bx = bp[0], by = bp[1], bz = bp[2];
    const float s0 = bp[3], s1 = bp[4], s2 = bp[5];
    const float hmin = bp[6];
    const int cx = clampi((int)floorf((qx - bx) * s0), 0, GC - 1);
    const int cy = clampi((int)floorf((qy - by) * s1), 0, GC - 1);
    const int cz = clampi((int)floorf((qz - bz) * s2), 0, GC - 1);

    const unsigned* go = gOff + (size_t)g * (NCELL + 1);
    const float4*   gt = gT + (size_t)g * MM;
    const unsigned* gi = gI + (size_t)g * MM;

    unsigned long long best = ~0ull;
    float fbest = INFINITY;

    for (int r = 0; r < GC; ++r) {
        if (r >= 2) {
            // any unscanned target is >= (r-1)*hmin away (proof holds for
            // clamped/out-of-box queries); 0.01 margin covers fp cancellation
            const float lb = (float)(r - 1) * hmin;
            if (fbest <= fmaf(lb, lb, 7.99f)) break;
        }
        const int z0 = cz - r < 0 ? 0 : cz - r;
        const int z1 = cz + r > GC - 1 ? GC - 1 : cz + r;
        for (int zz = z0; zz <= z1; ++zz) {
            const int adz = zz > cz ? zz - cz : cz - zz;
            const int y0 = cy - r < 0 ? 0 : cy - r;
            const int y1 = cy + r > GC - 1 ? GC - 1 : cy + r;
            for (int yy = y0; yy <= y1; ++yy) {
                const int ady = yy > cy ? yy - cy : cy - yy;
                const int x0 = cx - r < 0 ? 0 : cx - r;
                const int x1 = cx + r > GC - 1 ? GC - 1 : cx + r;
                for (int xx = x0; xx <= x1; ++xx) {
                    const int adx = xx > cx ? xx - cx : cx - xx;
                    int am = adx > ady ? adx : ady;
                    am = am > adz ? am : adz;
                    if (am != r) continue;           // Chebyshev shell only
                    const int c = (zz * GC + yy) * GC + xx;
                    const unsigned p0 = go[c];
                    const unsigned p1 = go[c + 1];
                    for (unsigned p = p0; p < p1; ++p) {
                        const float4 t = gt[p];
                        const float d2 = fmaf(m2x, t.x,
                                          fmaf(m2y, t.y,
                                           fmaf(m2z, t.z, t.w)));
                        const float f = d2 + q28;    // ||t-q||^2 + 8 > 0
                        const unsigned long long kk =
                            ((unsigned long long)__float_as_uint(f) << 32) | gi[p];
                        if (kk < best) { best = kk; fbest = f; }
                    }
                }
            }
        }
    }
    keys[(((size_t)mod * BB + b) * NN) + n] = best;
}

// ---------------- pass 2: unpack winner, compute loss terms -----------------
__global__ __launch_bounds__(TPB) void nn_loss_pass2(
    const float* __restrict__ noisy, const float* __restrict__ clean,
    const float* __restrict__ seeds, const float* __restrict__ stds,
    const float* __restrict__ disp,  const float* __restrict__ noise,
    const unsigned long long* __restrict__ keys,
    float* __restrict__ partials)
{
    __shared__ float red[TPB / 64];
    const int tid = threadIdx.x;
    const int b   = blockIdx.y;
    const int mod = blockIdx.z;
    const int n   = blockIdx.x * TPB + tid;

    const float sx = seeds[b * 3 + 0];
    const float sy = seeds[b * 3 + 1];
    const float sz = seeds[b * 3 + 2];
    float nstd = 0.0f;
    if (mod == 0) nstd = stds[b] * 0.25f;
    else if (mod == 1) nstd = stds[b] * 0.0625f;

    float qx = noisy[((size_t)b * NN + n) * 3 + 0] - sx;
    float qy = noisy[((size_t)b * NN + n) * 3 + 1] - sy;
    float qz = noisy[((size_t)b * NN + n) * 3 + 2] - sz;
    for (int j = 0; j < mod; ++j) {
        const size_t o = (((size_t)j * BB + b) * NN + n) * 3;
        qx += disp[o + 0]; qy += disp[o + 1]; qz += disp[o + 2];
    }
    const size_t od = (((size_t)mod * BB + b) * NN + n) * 3;
    const float dxp = disp[od + 0];
    const float dyp = disp[od + 1];
    const float dzp = disp[od + 2];

    const unsigned gidx =
        (unsigned)(keys[(((size_t)mod * BB + b) * NN) + n] & 0xFFFFFFFFull);

    const int set = (mod < 2) ? mod : 2;
    float tx, ty, tz; TGT_XYZ(set, b, (int)gidx, tx, ty, tz);

    const float ex = dxp - (tx - qx);
    const float ey = dyp - (ty - qy);
    const float ez = dzp - (tz - qz);
    float v = fmaf(ex, ex, fmaf(ey, ey, ez * ez));

    for (int o = 32; o; o >>= 1) v += __shfl_down(v, o);
    if ((tid & 63) == 0) red[tid >> 6] = v;
    __syncthreads();
    if (tid == 0) {
        const float s = red[0] + red[1] + red[2] + red[3];
        partials[(((size_t)mod * BB + b) * NXBLK2) + blockIdx.x] = s;
    }
}

__global__ void finalize_kernel(const float* __restrict__ partials, float* __restrict__ out) {
    float s = 0.0f;
    for (int k = threadIdx.x; k < NPART; k += 64) s += partials[k];
    for (int o = 32; o; o >>= 1) s += __shfl_down(s, o);
    if (threadIdx.x == 0) {
        out[0] = s * (1.0f / BB);
        out[1] = s * (1.0f / BB);
    }
}

// ---------------- monolithic dense fallback (2 KiB ws) ----------------------
#define TM 768
__global__ __launch_bounds__(TPB) void nn_loss_kernel(
    const float* __restrict__ noisy, const float* __restrict__ clean,
    const float* __restrict__ seeds, const float* __restrict__ stds,
    const float* __restrict__ disp,  const float* __restrict__ noise,
    float* __restrict__ partials)
{
    __shared__ float4 tgt[TM];
    __shared__ float red[TPB / 64];
    const int tid = threadIdx.x;
    const int b = blockIdx.y, mod = blockIdx.z;
    const int n = blockIdx.x * TPB + tid;
    const float sx = seeds[b*3+0], sy = seeds[b*3+1], sz = seeds[b*3+2];
    float qx = noisy[((size_t)b*NN+n)*3+0] - sx;
    float qy = noisy[((size_t)b*NN+n)*3+1] - sy;
    float qz = noisy[((size_t)b*NN+n)*3+2] - sz;
    for (int j = 0; j < mod; ++j) {
        const size_t o = (((size_t)j*BB + b)*NN + n)*3;
        qx += disp[o+0]; qy += disp[o+1]; qz += disp[o+2];
    }
    const size_t od = (((size_t)mod*BB + b)*NN + n)*3;
    const float dxp = disp[od+0], dyp = disp[od+1], dzp = disp[od+2];
    float nstd = 0.0f;
    if (mod == 0) nstd = stds[b]*0.25f; else if (mod == 1) nstd = stds[b]*0.0625f;
    const bool nt = (mod < 2);
    const float m2x = -2.0f*qx, m2y = -2.0f*qy, m2z = -2.0f*qz;
    float best = INFINITY; int bestm = 0;
    for (int mt = 0; mt < MM; mt += TM) {
        __syncthreads();
        for (int k = tid; k < TM; k += TPB) {
            const int m = mt + k;
            const size_t oc = ((size_t)b*MM + m)*3;
            float tx = clean[oc+0]-sx, ty = clean[oc+1]-sy, tz = clean[oc+2]-sz;
            if (nt) {
                const size_t on = (((size_t)mod*BB + b)*MM + m)*3;
                tx = fmaf(noise[on+0], nstd, tx);
                ty = fmaf(noise[on+1], nstd, ty);
                tz = fmaf(noise[on+2], nstd, tz);
            }
            tgt[k] = make_float4(tx, ty, tz, fmaf(tx,tx,fmaf(ty,ty,tz*tz)));
        }
        __syncthreads();
        #pragma unroll 8
        for (int k = 0; k < TM; ++k) {
            const float4 t = tgt[k];
            const float d2 = fmaf(m2x, t.x, fmaf(m2y, t.y, fmaf(m2z, t.z, t.w)));
            if (d2 < best) { best = d2; bestm = mt + k; }
        }
    }
    const size_t oc = ((size_t)b*MM + bestm)*3;
    float tx = clean[oc+0]-sx, ty = clean[oc+1]-sy, tz = clean[oc+2]-sz;
    if (nt) {
        const size_t on = (((size_t)mod*BB + b)*MM + bestm)*3;
        tx = fmaf(noise[on+0], nstd, tx);
        ty = fmaf(noise[on+1], nstd, ty);
        tz = fmaf(noise[on+2], nstd, tz);
    }
    const float ex = dxp - (tx - qx), ey = dyp - (ty - qy), ez = dzp - (tz - qz);
    float v = fmaf(ex, ex, fmaf(ey, ey, ez*ez));
    for (int o = 32; o; o >>= 1) v += __shfl_down(v, o);
    if ((tid & 63) == 0) red[tid >> 6] = v;
    __syncthreads();
    if (tid == 0)
        partials[(((size_t)mod*BB + b)*NXBLK2) + blockIdx.x] = red[0]+red[1]+red[2]+red[3];
}

extern "C" void kernel_launch(void* const* d_in, const int* in_sizes, int n_in,
                              void* d_out, int out_size, void* d_ws, size_t ws_size,
                              hipStream_t stream) {
    const float* noisy = (const float*)d_in[0];
    const float* clean = (const float*)d_in[1];
    const float* seeds = (const float*)d_in[2];
    const float* stds  = (const float*)d_in[3];
    const float* disp  = (const float*)d_in[4];
    const float* noise = (const float*)d_in[5];
    float* out = (float*)d_out;

    if (ws_size >= WS_NEED) {
        char* base = (char*)d_ws;
        unsigned* gOff = (unsigned*)(base);
        float4*   gT   = (float4*)(base + OFF_GT);
        unsigned* gI   = (unsigned*)(base + OFF_GI);
        float*    gBox = (float*)(base + OFF_GBOX);
        unsigned long long* keys = (unsigned long long*)(base + OFF_KEYS);
        float* partials = (float*)(base + OFF_PART);

        build_kernel<<<NG, TPB, 0, stream>>>(clean, seeds, stds, noise,
                                             gOff, gT, gI, gBox);
        dim3 gq(NXBLK2, BB, NMOD);
        query_kernel<<<gq, TPB, 0, stream>>>(noisy, seeds, disp,
                                             gOff, gT, gI, gBox, keys);
        nn_loss_pass2<<<gq, TPB, 0, stream>>>(noisy, clean, seeds, stds, disp,
                                              noise, keys, partials);
        finalize_kernel<<<1, 64, 0, stream>>>(partials, out);
    } else {
        float* partials = (float*)d_ws;
        dim3 grid(NXBLK2, BB, NMOD);
        nn_loss_kernel<<<grid, TPB, 0, stream>>>(noisy, clean, seeds, stds,
                                                 disp, noise, partials);
        finalize_kernel<<<1, 64, 0, stream>>>(partials, out);
    }
}

// Round 13
// 2326.766 us; speedup vs baseline: 5.9542x; 5.9542x over previous
//
#include <hip/hip_runtime.h>
#include <math.h>

#define NMOD 4
#define BB   8
#define NN   4096
#define MM   4608
#define TPB  256
#define NSET 3                      // target sets: mod0-noise, mod1-noise, clean
#define NG   (NSET * BB)            // 24 grids
#define GC   16                     // cells per dimension
#define NCELL (GC * GC * GC)        // 4096
#define QCOUNT (NMOD * BB * NN)     // 131072
#define NXBLK2 (NN / TPB)           // 16
#define NPART  (NMOD * BB * NXBLK2) // 512

// ---- workspace layout (compile-time, 256B aligned) ----
#define SZ_GOFF  ((size_t)NG * (NCELL + 1) * 4)
#define OFF_GT   ((SZ_GOFF + 255) & ~(size_t)255)
#define SZ_GT    ((size_t)NG * MM * 16)
#define OFF_GI   ((OFF_GT + SZ_GT + 255) & ~(size_t)255)
#define SZ_GI    ((size_t)NG * MM * 4)
#define OFF_GBOX ((OFF_GI + SZ_GI + 255) & ~(size_t)255)
#define SZ_GBOX  ((size_t)NG * 8 * 4)
#define OFF_KEYS ((OFF_GBOX + SZ_GBOX + 255) & ~(size_t)255)
#define SZ_KEYS  ((size_t)QCOUNT * 8)
#define OFF_PART ((OFF_KEYS + SZ_KEYS + 255) & ~(size_t)255)
#define WS_NEED  (OFF_PART + (size_t)NPART * 4)

static __device__ __forceinline__ int clampi(int v, int lo, int hi) {
    return v < lo ? lo : (v > hi ? hi : v);
}

// target coordinates, identical formula everywhere (build, pass2)
#define TGT_XYZ(SET, B, M, TX, TY, TZ) do {                               \
        const size_t oc_ = ((size_t)(B) * MM + (M)) * 3;                  \
        TX = clean[oc_ + 0] - sx;                                         \
        TY = clean[oc_ + 1] - sy;                                         \
        TZ = clean[oc_ + 2] - sz;                                         \
        if ((SET) < 2) {                                                  \
            const size_t on_ = (((size_t)(SET) * BB + (B)) * MM + (M)) * 3;\
            TX = fmaf(noise[on_ + 0], nstd, TX);                          \
            TY = fmaf(noise[on_ + 1], nstd, TY);                          \
            TZ = fmaf(noise[on_ + 2], nstd, TZ);                          \
        }                                                                 \
    } while (0)

// ---------------- grid build: one block per (set,b) grid --------------------
__global__ __launch_bounds__(TPB) void build_kernel(
    const float* __restrict__ clean, const float* __restrict__ seeds,
    const float* __restrict__ stds,  const float* __restrict__ noise,
    unsigned* __restrict__ gOff, float4* __restrict__ gT,
    unsigned* __restrict__ gI,   float* __restrict__ gBox)
{
    __shared__ unsigned cnt[NCELL];      // 16384 B
    __shared__ unsigned part[TPB];
    __shared__ float sb[4][6];
    __shared__ float boxl[8];

    const int g   = blockIdx.x;
    const int set = g / BB;
    const int b   = g % BB;
    const int tid = threadIdx.x;

    const float sx = seeds[b * 3 + 0];
    const float sy = seeds[b * 3 + 1];
    const float sz = seeds[b * 3 + 2];
    float nstd = 0.0f;
    if (set == 0) nstd = stds[b] * 0.25f;
    else if (set == 1) nstd = stds[b] * 0.0625f;

    // --- phase 1: bounding box ---
    float mnx = INFINITY, mny = INFINITY, mnz = INFINITY;
    float mxx = -INFINITY, mxy = -INFINITY, mxz = -INFINITY;
    for (int m = tid; m < MM; m += TPB) {
        float tx, ty, tz; TGT_XYZ(set, b, m, tx, ty, tz);
        mnx = fminf(mnx, tx); mny = fminf(mny, ty); mnz = fminf(mnz, tz);
        mxx = fmaxf(mxx, tx); mxy = fmaxf(mxy, ty); mxz = fmaxf(mxz, tz);
    }
    for (int o = 32; o; o >>= 1) {
        mnx = fminf(mnx, __shfl_down(mnx, o));
        mny = fminf(mny, __shfl_down(mny, o));
        mnz = fminf(mnz, __shfl_down(mnz, o));
        mxx = fmaxf(mxx, __shfl_down(mxx, o));
        mxy = fmaxf(mxy, __shfl_down(mxy, o));
        mxz = fmaxf(mxz, __shfl_down(mxz, o));
    }
    if ((tid & 63) == 0) {
        const int w = tid >> 6;
        sb[w][0] = mnx; sb[w][1] = mny; sb[w][2] = mnz;
        sb[w][3] = mxx; sb[w][4] = mxy; sb[w][5] = mxz;
    }
    __syncthreads();
    if (tid == 0) {
        float n0 = fminf(fminf(sb[0][0], sb[1][0]), fminf(sb[2][0], sb[3][0]));
        float n1 = fminf(fminf(sb[0][1], sb[1][1]), fminf(sb[2][1], sb[3][1]));
        float n2 = fminf(fminf(sb[0][2], sb[1][2]), fminf(sb[2][2], sb[3][2]));
        float x0 = fmaxf(fmaxf(sb[0][3], sb[1][3]), fmaxf(sb[2][3], sb[3][3]));
        float x1 = fmaxf(fmaxf(sb[0][4], sb[1][4]), fmaxf(sb[2][4], sb[3][4]));
        float x2 = fmaxf(fmaxf(sb[0][5], sb[1][5]), fmaxf(sb[2][5], sb[3][5]));
        const float e0 = x0 - n0 + 1e-5f, e1 = x1 - n1 + 1e-5f, e2 = x2 - n2 + 1e-5f;
        boxl[0] = n0; boxl[1] = n1; boxl[2] = n2;
        boxl[3] = (float)GC / e0; boxl[4] = (float)GC / e1; boxl[5] = (float)GC / e2;
        boxl[6] = fminf(e0 / GC, fminf(e1 / GC, e2 / GC));   // hmin
        boxl[7] = 0.0f;
        for (int i = 0; i < 8; ++i) gBox[g * 8 + i] = boxl[i];
    }
    __syncthreads();
    const float bx = boxl[0], by = boxl[1], bz = boxl[2];
    const float s0 = boxl[3], s1 = boxl[4], s2 = boxl[5];

    // --- phase 2: zero counts ---
    for (int c = tid; c < NCELL; c += TPB) cnt[c] = 0;
    __syncthreads();

    // --- phase 3: count ---
    for (int m = tid; m < MM; m += TPB) {
        float tx, ty, tz; TGT_XYZ(set, b, m, tx, ty, tz);
        const int cx = clampi((int)floorf((tx - bx) * s0), 0, GC - 1);
        const int cy = clampi((int)floorf((ty - by) * s1), 0, GC - 1);
        const int cz = clampi((int)floorf((tz - bz) * s2), 0, GC - 1);
        atomicAdd(&cnt[(cz * GC + cy) * GC + cx], 1u);
    }
    __syncthreads();

    // --- phase 4: exclusive scan (cnt -> starts), write gOff ---
    constexpr int CPT = NCELL / TPB;   // 16
    {
        const int base = tid * CPT;
        unsigned s = 0;
        for (int i = 0; i < CPT; ++i) s += cnt[base + i];
        part[tid] = s;
    }
    __syncthreads();
    if (tid == 0) {
        unsigned r = 0;
        for (int i = 0; i < TPB; ++i) { const unsigned t = part[i]; part[i] = r; r += t; }
    }
    __syncthreads();
    {
        const int base = tid * CPT;
        unsigned r = part[tid];
        unsigned* go = gOff + (size_t)g * (NCELL + 1);
        for (int i = 0; i < CPT; ++i) {
            const unsigned t = cnt[base + i];
            cnt[base + i] = r;          // becomes the scatter cursor
            go[base + i]  = r;
            r += t;
        }
        if (tid == 0) go[NCELL] = MM;
    }
    __syncthreads();

    // --- phase 5: scatter ---
    float4*   gt = gT + (size_t)g * MM;
    unsigned* gi = gI + (size_t)g * MM;
    for (int m = tid; m < MM; m += TPB) {
        float tx, ty, tz; TGT_XYZ(set, b, m, tx, ty, tz);
        const float tw = fmaf(tx, tx, fmaf(ty, ty, tz * tz));
        const int cx = clampi((int)floorf((tx - bx) * s0), 0, GC - 1);
        const int cy = clampi((int)floorf((ty - by) * s1), 0, GC - 1);
        const int cz = clampi((int)floorf((tz - bz) * s2), 0, GC - 1);
        const unsigned pos = atomicAdd(&cnt[(cz * GC + cy) * GC + cx], 1u);
        gt[pos] = make_float4(tx, ty, tz, tw);
        gi[pos] = (unsigned)m;
    }
}

// ---------------- query: exact ring-bounded NN (row-span scan) --------------
__global__ __launch_bounds__(TPB) void query_kernel(
    const float* __restrict__ noisy, const float* __restrict__ seeds,
    const float* __restrict__ disp,
    const unsigned* __restrict__ gOff, const float4* __restrict__ gT,
    const unsigned* __restrict__ gI,   const float* __restrict__ gBox,
    unsigned long long* __restrict__ keys)
{
    const int tid = threadIdx.x;
    const int b   = blockIdx.y;
    const int mod = blockIdx.z;
    const int n   = blockIdx.x * TPB + tid;
    const int set = (mod < 2) ? mod : 2;
    const int g   = set * BB + b;

    const float sx = seeds[b * 3 + 0];
    const float sy = seeds[b * 3 + 1];
    const float sz = seeds[b * 3 + 2];

    float qx = noisy[((size_t)b * NN + n) * 3 + 0] - sx;
    float qy = noisy[((size_t)b * NN + n) * 3 + 1] - sy;
    float qz = noisy[((size_t)b * NN + n) * 3 + 2] - sz;
    for (int j = 0; j < mod; ++j) {
        const size_t o = (((size_t)j * BB + b) * NN + n) * 3;
        qx += disp[o + 0]; qy += disp[o + 1]; qz += disp[o + 2];
    }
    const float q2  = fmaf(qx, qx, fmaf(qy, qy, qz * qz));
    const float q28 = q2 + 8.0f;
    const float m2x = -2.0f * qx, m2y = -2.0f * qy, m2z = -2.0f * qz;

    const float* bp = gBox + g * 8;
    const float bx = bp[0], by = bp[1], bz = bp[2];
    const float s0 = bp[3], s1 = bp[4], s2 = bp[5];
    const float hmin = bp[6];
    const int cx = clampi((int)floorf((qx - bx) * s0), 0, GC - 1);
    const int cy = clampi((int)floorf((qy - by) * s1), 0, GC - 1);
    const int cz = clampi((int)floorf((qz - bz) * s2), 0, GC - 1);

    const unsigned* go = gOff + (size_t)g * (NCELL + 1);
    const float4*   gt = gT + (size_t)g * MM;
    const unsigned* gi = gI + (size_t)g * MM;

    unsigned long long best = ~0ull;
    float bq = INFINITY;                 // true squared NN distance so far

    // scan a contiguous cell span [CA, CB] (cells contiguous along x)
#define SCAN_SPAN(CA, CB) do {                                            \
        const unsigned p0_ = go[(CA)];                                    \
        const unsigned p1_ = go[(CB) + 1];                                \
        for (unsigned p = p0_; p < p1_; ++p) {                            \
            const float4 t = gt[p];                                       \
            const float d2 = fmaf(m2x, t.x,                               \
                              fmaf(m2y, t.y, fmaf(m2z, t.z, t.w)));       \
            const float f = d2 + q28;    /* ||t-q||^2 + 8 > 0 */          \
            const unsigned long long kk =                                 \
                ((unsigned long long)__float_as_uint(f) << 32) | gi[p];   \
            if (kk < best) { best = kk; bq = f - 8.0f; }                  \
        }                                                                 \
    } while (0)

    for (int r = 0; r < GC; ++r) {
        if (r >= 2) {
            // unscanned targets are >= (r-1)*hmin away in TRUE distance;
            // compare against true squared distance bq (NOT bq+q2 - r12 bug).
            // 0.02%+1e-3 margin covers fp cancellation (~1e-4 abs).
            const float lb = (float)(r - 1) * hmin;
            if (bq * 1.0002f + 1e-3f <= lb * lb) break;
        }
        const int z0 = cz - r < 0 ? 0 : cz - r;
        const int z1 = cz + r > GC - 1 ? GC - 1 : cz + r;
        for (int zz = z0; zz <= z1; ++zz) {
            const int adz = zz > cz ? zz - cz : cz - zz;
            const int y0 = cy - r < 0 ? 0 : cy - r;
            const int y1 = cy + r > GC - 1 ? GC - 1 : cy + r;
            for (int yy = y0; yy <= y1; ++yy) {
                const int ady = yy > cy ? yy - cy : cy - yy;
                const int rowb = (zz * GC + yy) * GC;
                if (adz == r || ady == r) {
                    // whole row lies on the Chebyshev-r shell: one span
                    const int x0 = cx - r < 0 ? 0 : cx - r;
                    const int x1 = cx + r > GC - 1 ? GC - 1 : cx + r;
                    SCAN_SPAN(rowb + x0, rowb + x1);
                } else {
                    // interior row: only the two x-extremes are on the shell
                    if (cx - r >= 0)     SCAN_SPAN(rowb + cx - r, rowb + cx - r);
                    if (cx + r <= GC - 1) SCAN_SPAN(rowb + cx + r, rowb + cx + r);
                }
            }
        }
    }
#undef SCAN_SPAN
    keys[(((size_t)mod * BB + b) * NN) + n] = best;
}

// ---------------- pass 2: unpack winner, compute loss terms -----------------
__global__ __launch_bounds__(TPB) void nn_loss_pass2(
    const float* __restrict__ noisy, const float* __restrict__ clean,
    const float* __restrict__ seeds, const float* __restrict__ stds,
    const float* __restrict__ disp,  const float* __restrict__ noise,
    const unsigned long long* __restrict__ keys,
    float* __restrict__ partials)
{
    __shared__ float red[TPB / 64];
    const int tid = threadIdx.x;
    const int b   = blockIdx.y;
    const int mod = blockIdx.z;
    const int n   = blockIdx.x * TPB + tid;

    const float sx = seeds[b * 3 + 0];
    const float sy = seeds[b * 3 + 1];
    const float sz = seeds[b * 3 + 2];
    float nstd = 0.0f;
    if (mod == 0) nstd = stds[b] * 0.25f;
    else if (mod == 1) nstd = stds[b] * 0.0625f;

    float qx = noisy[((size_t)b * NN + n) * 3 + 0] - sx;
    float qy = noisy[((size_t)b * NN + n) * 3 + 1] - sy;
    float qz = noisy[((size_t)b * NN + n) * 3 + 2] - sz;
    for (int j = 0; j < mod; ++j) {
        const size_t o = (((size_t)j * BB + b) * NN + n) * 3;
        qx += disp[o + 0]; qy += disp[o + 1]; qz += disp[o + 2];
    }
    const size_t od = (((size_t)mod * BB + b) * NN + n) * 3;
    const float dxp = disp[od + 0];
    const float dyp = disp[od + 1];
    const float dzp = disp[od + 2];

    const unsigned gidx =
        (unsigned)(keys[(((size_t)mod * BB + b) * NN) + n] & 0xFFFFFFFFull);

    const int set = (mod < 2) ? mod : 2;
    float tx, ty, tz; TGT_XYZ(set, b, (int)gidx, tx, ty, tz);

    const float ex = dxp - (tx - qx);
    const float ey = dyp - (ty - qy);
    const float ez = dzp - (tz - qz);
    float v = fmaf(ex, ex, fmaf(ey, ey, ez * ez));

    for (int o = 32; o; o >>= 1) v += __shfl_down(v, o);
    if ((tid & 63) == 0) red[tid >> 6] = v;
    __syncthreads();
    if (tid == 0) {
        const float s = red[0] + red[1] + red[2] + red[3];
        partials[(((size_t)mod * BB + b) * NXBLK2) + blockIdx.x] = s;
    }
}

__global__ void finalize_kernel(const float* __restrict__ partials, float* __restrict__ out) {
    float s = 0.0f;
    for (int k = threadIdx.x; k < NPART; k += 64) s += partials[k];
    for (int o = 32; o; o >>= 1) s += __shfl_down(s, o);
    if (threadIdx.x == 0) {
        out[0] = s * (1.0f / BB);
        out[1] = s * (1.0f / BB);
    }
}

// ---------------- monolithic dense fallback (2 KiB ws) ----------------------
#define TM 768
__global__ __launch_bounds__(TPB) void nn_loss_kernel(
    const float* __restrict__ noisy, const float* __restrict__ clean,
    const float* __restrict__ seeds, const float* __restrict__ stds,
    const float* __restrict__ disp,  const float* __restrict__ noise,
    float* __restrict__ partials)
{
    __shared__ float4 tgt[TM];
    __shared__ float red[TPB / 64];
    const int tid = threadIdx.x;
    const int b = blockIdx.y, mod = blockIdx.z;
    const int n = blockIdx.x * TPB + tid;
    const float sx = seeds[b*3+0], sy = seeds[b*3+1], sz = seeds[b*3+2];
    float qx = noisy[((size_t)b*NN+n)*3+0] - sx;
    float qy = noisy[((size_t)b*NN+n)*3+1] - sy;
    float qz = noisy[((size_t)b*NN+n)*3+2] - sz;
    for (int j = 0; j < mod; ++j) {
        const size_t o = (((size_t)j*BB + b)*NN + n)*3;
        qx += disp[o+0]; qy += disp[o+1]; qz += disp[o+2];
    }
    const size_t od = (((size_t)mod*BB + b)*NN + n)*3;
    const float dxp = disp[od+0], dyp = disp[od+1], dzp = disp[od+2];
    float nstd = 0.0f;
    if (mod == 0) nstd = stds[b]*0.25f; else if (mod == 1) nstd = stds[b]*0.0625f;
    const bool nt = (mod < 2);
    const float m2x = -2.0f*qx, m2y = -2.0f*qy, m2z = -2.0f*qz;
    float best = INFINITY; int bestm = 0;
    for (int mt = 0; mt < MM; mt += TM) {
        __syncthreads();
        for (int k = tid; k < TM; k += TPB) {
            const int m = mt + k;
            const size_t oc = ((size_t)b*MM + m)*3;
            float tx = clean[oc+0]-sx, ty = clean[oc+1]-sy, tz = clean[oc+2]-sz;
            if (nt) {
                const size_t on = (((size_t)mod*BB + b)*MM + m)*3;
                tx = fmaf(noise[on+0], nstd, tx);
                ty = fmaf(noise[on+1], nstd, ty);
                tz = fmaf(noise[on+2], nstd, tz);
            }
            tgt[k] = make_float4(tx, ty, tz, fmaf(tx,tx,fmaf(ty,ty,tz*tz)));
        }
        __syncthreads();
        #pragma unroll 8
        for (int k = 0; k < TM; ++k) {
            const float4 t = tgt[k];
            const float d2 = fmaf(m2x, t.x, fmaf(m2y, t.y, fmaf(m2z, t.z, t.w)));
            if (d2 < best) { best = d2; bestm = mt + k; }
        }
    }
    const size_t oc = ((size_t)b*MM + bestm)*3;
    float tx = clean[oc+0]-sx, ty = clean[oc+1]-sy, tz = clean[oc+2]-sz;
    if (nt) {
        const size_t on = (((size_t)mod*BB + b)*MM + bestm)*3;
        tx = fmaf(noise[on+0], nstd, tx);
        ty = fmaf(noise[on+1], nstd, ty);
        tz = fmaf(noise[on+2], nstd, tz);
    }
    const float ex = dxp - (tx - qx), ey = dyp - (ty - qy), ez = dzp - (tz - qz);
    float v = fmaf(ex, ex, fmaf(ey, ey, ez*ez));
    for (int o = 32; o; o >>= 1) v += __shfl_down(v, o);
    if ((tid & 63) == 0) red[tid >> 6] = v;
    __syncthreads();
    if (tid == 0)
        partials[(((size_t)mod*BB + b)*NXBLK2) + blockIdx.x] = red[0]+red[1]+red[2]+red[3];
}

extern "C" void kernel_launch(void* const* d_in, const int* in_sizes, int n_in,
                              void* d_out, int out_size, void* d_ws, size_t ws_size,
                              hipStream_t stream) {
    const float* noisy = (const float*)d_in[0];
    const float* clean = (const float*)d_in[1];
    const float* seeds = (const float*)d_in[2];
    const float* stds  = (const float*)d_in[3];
    const float* disp  = (const float*)d_in[4];
    const float* noise = (const float*)d_in[5];
    float* out = (float*)d_out;

    if (ws_size >= WS_NEED) {
        char* base = (char*)d_ws;
        unsigned* gOff = (unsigned*)(base);
        float4*   gT   = (float4*)(base + OFF_GT);
        unsigned* gI   = (unsigned*)(base + OFF_GI);
        float*    gBox = (float*)(base + OFF_GBOX);
        unsigned long long* keys = (unsigned long long*)(base + OFF_KEYS);
        float* partials = (float*)(base + OFF_PART);

        build_kernel<<<NG, TPB, 0, stream>>>(clean, seeds, stds, noise,
                                             gOff, gT, gI, gBox);
        dim3 gq(NXBLK2, BB, NMOD);
        query_kernel<<<gq, TPB, 0, stream>>>(noisy, seeds, disp,
                                             gOff, gT, gI, gBox, keys);
        nn_loss_pass2<<<gq, TPB, 0, stream>>>(noisy, clean, seeds, stds, disp,
                                              noise, keys, partials);
        finalize_kernel<<<1, 64, 0, stream>>>(partials, out);
    } else {
        float* partials = (float*)d_ws;
        dim3 grid(NXBLK2, BB, NMOD);
        nn_loss_kernel<<<grid, TPB, 0, stream>>>(noisy, clean, seeds, stds,
                                                 disp, noise, partials);
        finalize_kernel<<<1, 64, 0, stream>>>(partials, out);
    }
}

// Round 14
// 155.865 us; speedup vs baseline: 88.8853x; 14.9281x over previous
//
#include <hip/hip_runtime.h>
#include <math.h>

#define NMOD 4
#define BB   8
#define NN   4096
#define MM   4608
#define TPB  256
#define NSET 3                          // target sets: mod0, mod1, clean(mods 2,3)
#define NG   (NSET * BB)                // 24 tables

// ---- fast path geometry ----
#define QPT      8                      // queries per thread (named scalars)
#define QPB      (TPB * QPT)            // 2048 queries per block
#define NXB      (NN / QPB)             // 2
#define CH       16                     // chunk size for argmin bookkeeping
#define QCOUNT   (NMOD * BB * NN)       // 131072
#define NXBLK2   (NN / TPB)             // 16
#define NPART    (NMOD * BB * NXBLK2)   // 512

// ---- workspace layout ----
#define SZ_TBL   ((size_t)NG * MM * 16)                  // 1.77 MB float4 tables
#define OFF_KEYS ((SZ_TBL + 255) & ~(size_t)255)
#define KEYB(NSL) ((size_t)(NSL) * QCOUNT * 8)
#define WS_TIER(NSL) (OFF_KEYS + KEYB(NSL) + (size_t)NPART * 4)

static __device__ __forceinline__ float min3f(float a, float b, float c) {
    float d;
    asm("v_min3_f32 %0, %1, %2, %3" : "=v"(d) : "v"(a), "v"(b), "v"(c));
    return d;
}

// identical FMA chain in scan and rescan -> bit-exact equality
#define CHAIN(T, MX, MY, MZ) \
    fmaf(MX, (T).x, fmaf(MY, (T).y, fmaf(MZ, (T).z, (T).w)))

// ---------------- build: materialize seed-centered target tables ------------
__global__ __launch_bounds__(TPB) void build_tbl(
    const float* __restrict__ clean, const float* __restrict__ seeds,
    const float* __restrict__ stds,  const float* __restrict__ noise,
    float4* __restrict__ tbl)
{
    const int m   = blockIdx.x * TPB + threadIdx.x;   // [0, MM)
    const int g   = blockIdx.y;                        // [0, NG)
    const int set = g / BB;
    const int b   = g % BB;

    const float sx = seeds[b * 3 + 0];
    const float sy = seeds[b * 3 + 1];
    const float sz = seeds[b * 3 + 2];
    float nstd = 0.0f;
    if (set == 0) nstd = stds[b] * 0.25f;
    else if (set == 1) nstd = stds[b] * 0.0625f;

    const size_t oc = ((size_t)b * MM + m) * 3;
    float tx = clean[oc + 0] - sx;
    float ty = clean[oc + 1] - sy;
    float tz = clean[oc + 2] - sz;
    if (set < 2) {
        const size_t on = (((size_t)set * BB + b) * MM + m) * 3;
        tx = fmaf(noise[on + 0], nstd, tx);
        ty = fmaf(noise[on + 1], nstd, ty);
        tz = fmaf(noise[on + 2], nstd, tz);
    }
    const float tw = fmaf(tx, tx, fmaf(ty, ty, tz * tz));
    tbl[(size_t)g * MM + m] = make_float4(tx, ty, tz, tw);
}

// ---------------- pass 1: chunked min3 slice argmin, LDS-free ---------------
// Targets read via wave-uniform global loads (block-uniform index +
// __restrict__ -> s_load / broadcast L1 line). No DS pipe, no barrier.
template <int NSL>
__global__ __launch_bounds__(TPB, 4) void nn_min_kernel(
    const float* __restrict__ noisy, const float* __restrict__ seeds,
    const float* __restrict__ disp,  const float4* __restrict__ tbl,
    unsigned long long* __restrict__ keys)
{
    constexpr int SLICE_M = MM / NSL;
    constexpr int NCHUNK  = SLICE_M / CH;

    const int tid   = threadIdx.x;
    const int b     = blockIdx.y;
    const int mod   = blockIdx.z / NSL;
    const int sl    = blockIdx.z % NSL;
    const int mbase = sl * SLICE_M;
    const int nb    = blockIdx.x * QPB + tid;
    const int set   = (mod < 2) ? mod : 2;

    const float4* __restrict__ tb = tbl + (size_t)(set * BB + b) * MM + mbase;

    const float sx = seeds[b * 3 + 0];
    const float sy = seeds[b * 3 + 1];
    const float sz = seeds[b * 3 + 2];

    // ---- 8 queries, all named scalars (no arrays -> no scratch) ----
    float m2x0, m2y0, m2z0, m2x1, m2y1, m2z1, m2x2, m2y2, m2z2, m2x3, m2y3, m2z3;
    float m2x4, m2y4, m2z4, m2x5, m2y5, m2z5, m2x6, m2y6, m2z6, m2x7, m2y7, m2z7;

#define QSETUP(K, MX, MY, MZ) do {                                        \
        const int n = nb + (K) * TPB;                                     \
        const size_t o0 = ((size_t)b * NN + n) * 3;                       \
        float qx = noisy[o0 + 0] - sx;                                    \
        float qy = noisy[o0 + 1] - sy;                                    \
        float qz = noisy[o0 + 2] - sz;                                    \
        for (int j = 0; j < mod; ++j) {                                   \
            const size_t o = (((size_t)j * BB + b) * NN + n) * 3;         \
            qx += disp[o + 0]; qy += disp[o + 1]; qz += disp[o + 2];      \
        }                                                                 \
        MX = -2.0f * qx; MY = -2.0f * qy; MZ = -2.0f * qz;                \
    } while (0)

    QSETUP(0, m2x0, m2y0, m2z0); QSETUP(1, m2x1, m2y1, m2z1);
    QSETUP(2, m2x2, m2y2, m2z2); QSETUP(3, m2x3, m2y3, m2z3);
    QSETUP(4, m2x4, m2y4, m2z4); QSETUP(5, m2x5, m2y5, m2z5);
    QSETUP(6, m2x6, m2y6, m2z6); QSETUP(7, m2x7, m2y7, m2z7);
#undef QSETUP

    float bb0 = INFINITY, bb1 = INFINITY, bb2 = INFINITY, bb3 = INFINITY;
    float bb4 = INFINITY, bb5 = INFINITY, bb6 = INFINITY, bb7 = INFINITY;
    int cc0 = 0, cc1 = 0, cc2 = 0, cc3 = 0, cc4 = 0, cc5 = 0, cc6 = 0, cc7 = 0;

    for (int c = 0; c < NCHUNK; ++c) {
        float a0 = INFINITY, a1 = INFINITY, a2 = INFINITY, a3 = INFINITY;
        float a4 = INFINITY, a5 = INFINITY, a6 = INFINITY, a7 = INFINITY;

        #pragma unroll
        for (int u = 0; u < CH; u += 2) {
            const float4 t0 = tb[c * CH + u];
            const float4 t1 = tb[c * CH + u + 1];
#define EVAL2(MX, MY, MZ, A) do {                                         \
            const float d0 = CHAIN(t0, MX, MY, MZ);                       \
            const float d1 = CHAIN(t1, MX, MY, MZ);                       \
            A = min3f(d0, d1, A);                                         \
        } while (0)
            EVAL2(m2x0, m2y0, m2z0, a0);
            EVAL2(m2x1, m2y1, m2z1, a1);
            EVAL2(m2x2, m2y2, m2z2, a2);
            EVAL2(m2x3, m2y3, m2z3, a3);
            EVAL2(m2x4, m2y4, m2z4, a4);
            EVAL2(m2x5, m2y5, m2z5, a5);
            EVAL2(m2x6, m2y6, m2z6, a6);
            EVAL2(m2x7, m2y7, m2z7, a7);
#undef EVAL2
        }

#define CUPD(A, BV, CV) do {                                              \
        const bool c_ = (A) < (BV);                                       \
        BV = c_ ? (A) : (BV);                                             \
        CV = c_ ? c : (CV);                                               \
    } while (0)
        CUPD(a0, bb0, cc0); CUPD(a1, bb1, cc1);
        CUPD(a2, bb2, cc2); CUPD(a3, bb3, cc3);
        CUPD(a4, bb4, cc4); CUPD(a5, bb5, cc5);
        CUPD(a6, bb6, cc6); CUPD(a7, bb7, cc7);
#undef CUPD
    }

    unsigned long long* __restrict__ kslice = keys + (size_t)sl * QCOUNT
                                            + (((size_t)mod * BB + b) * NN);

    // rescan winning chunk (backward overwrite -> first match), pack, store
#define FINQ(K, MX, MY, MZ, BV, CV) do {                                  \
        int im = 0;                                                       \
        for (int u = CH - 1; u >= 0; --u) {                               \
            const float4 t = tb[(CV) * CH + u];                           \
            const float d = CHAIN(t, MX, MY, MZ);                         \
            im = (d == (BV)) ? ((CV) * CH + u) : im;                      \
        }                                                                 \
        const float q2 = 0.25f * fmaf(MX, MX, fmaf(MY, MY, (MZ) * (MZ)));\
        const float f = (BV) + q2 + 8.0f;                                 \
        const unsigned long long key =                                    \
            ((unsigned long long)__float_as_uint(f) << 32) |              \
            (unsigned int)(mbase + im);                                   \
        kslice[nb + (K) * TPB] = key;                                     \
    } while (0)

    FINQ(0, m2x0, m2y0, m2z0, bb0, cc0);
    FINQ(1, m2x1, m2y1, m2z1, bb1, cc1);
    FINQ(2, m2x2, m2y2, m2z2, bb2, cc2);
    FINQ(3, m2x3, m2y3, m2z3, bb3, cc3);
    FINQ(4, m2x4, m2y4, m2z4, bb4, cc4);
    FINQ(5, m2x5, m2y5, m2z5, bb5, cc5);
    FINQ(6, m2x6, m2y6, m2z6, bb6, cc6);
    FINQ(7, m2x7, m2y7, m2z7, bb7, cc7);
#undef FINQ
}

// ---------------- pass 2: combine slices, unpack winner, loss ---------------
template <int NSL>
__global__ __launch_bounds__(TPB) void nn_loss_pass2(
    const float* __restrict__ noisy, const float* __restrict__ seeds,
    const float* __restrict__ disp,  const float4* __restrict__ tbl,
    const unsigned long long* __restrict__ keys,
    float* __restrict__ partials)
{
    __shared__ float red[TPB / 64];
    const int tid = threadIdx.x;
    const int b   = blockIdx.y;
    const int mod = blockIdx.z;
    const int n   = blockIdx.x * TPB + tid;
    const int set = (mod < 2) ? mod : 2;

    const float sx = seeds[b * 3 + 0];
    const float sy = seeds[b * 3 + 1];
    const float sz = seeds[b * 3 + 2];

    float qx = noisy[((size_t)b * NN + n) * 3 + 0] - sx;
    float qy = noisy[((size_t)b * NN + n) * 3 + 1] - sy;
    float qz = noisy[((size_t)b * NN + n) * 3 + 2] - sz;
    for (int j = 0; j < mod; ++j) {
        const size_t o = (((size_t)j * BB + b) * NN + n) * 3;
        qx += disp[o + 0]; qy += disp[o + 1]; qz += disp[o + 2];
    }
    const size_t od = (((size_t)mod * BB + b) * NN + n) * 3;
    const float dxp = disp[od + 0];
    const float dyp = disp[od + 1];
    const float dzp = disp[od + 2];

    const size_t q = (((size_t)mod * BB + b) * NN) + n;
    unsigned long long k = keys[q];
    #pragma unroll
    for (int s = 1; s < NSL; ++s) {
        const unsigned long long v = keys[(size_t)s * QCOUNT + q];
        k = v < k ? v : k;
    }
    const unsigned gidx = (unsigned)(k & 0xFFFFFFFFull);

    const float4 t = tbl[(size_t)(set * BB + b) * MM + gidx];
    const float ex = dxp - (t.x - qx);
    const float ey = dyp - (t.y - qy);
    const float ez = dzp - (t.z - qz);
    float v = fmaf(ex, ex, fmaf(ey, ey, ez * ez));

    for (int o = 32; o; o >>= 1) v += __shfl_down(v, o);
    if ((tid & 63) == 0) red[tid >> 6] = v;
    __syncthreads();
    if (tid == 0) {
        const float s = red[0] + red[1] + red[2] + red[3];
        partials[(((size_t)mod * BB + b) * NXBLK2) + blockIdx.x] = s;
    }
}

__global__ void finalize_kernel(const float* __restrict__ partials, float* __restrict__ out) {
    float s = 0.0f;
    for (int k = threadIdx.x; k < NPART; k += 64) s += partials[k];
    for (int o = 32; o; o >>= 1) s += __shfl_down(s, o);
    if (threadIdx.x == 0) {
        out[0] = s * (1.0f / BB);
        out[1] = s * (1.0f / BB);
    }
}

// ---------------- monolithic dense fallback (2 KiB ws) ----------------------
#define TM 768
__global__ __launch_bounds__(TPB) void nn_loss_kernel(
    const float* __restrict__ noisy, const float* __restrict__ clean,
    const float* __restrict__ seeds, const float* __restrict__ stds,
    const float* __restrict__ disp,  const float* __restrict__ noise,
    float* __restrict__ partials)
{
    __shared__ float4 tgt[TM];
    __shared__ float red[TPB / 64];
    const int tid = threadIdx.x;
    const int b = blockIdx.y, mod = blockIdx.z;
    const int n = blockIdx.x * TPB + tid;
    const float sx = seeds[b*3+0], sy = seeds[b*3+1], sz = seeds[b*3+2];
    float qx = noisy[((size_t)b*NN+n)*3+0] - sx;
    float qy = noisy[((size_t)b*NN+n)*3+1] - sy;
    float qz = noisy[((size_t)b*NN+n)*3+2] - sz;
    for (int j = 0; j < mod; ++j) {
        const size_t o = (((size_t)j*BB + b)*NN + n)*3;
        qx += disp[o+0]; qy += disp[o+1]; qz += disp[o+2];
    }
    const size_t od = (((size_t)mod*BB + b)*NN + n)*3;
    const float dxp = disp[od+0], dyp = disp[od+1], dzp = disp[od+2];
    float nstd = 0.0f;
    if (mod == 0) nstd = stds[b]*0.25f; else if (mod == 1) nstd = stds[b]*0.0625f;
    const bool nt = (mod < 2);
    const float m2x = -2.0f*qx, m2y = -2.0f*qy, m2z = -2.0f*qz;
    float best = INFINITY; int bestm = 0;
    for (int mt = 0; mt < MM; mt += TM) {
        __syncthreads();
        for (int k = tid; k < TM; k += TPB) {
            const int m = mt + k;
            const size_t oc = ((size_t)b*MM + m)*3;
            float tx = clean[oc+0]-sx, ty = clean[oc+1]-sy, tz = clean[oc+2]-sz;
            if (nt) {
                const size_t on = (((size_t)mod*BB + b)*MM + m)*3;
                tx = fmaf(noise[on+0], nstd, tx);
                ty = fmaf(noise[on+1], nstd, ty);
                tz = fmaf(noise[on+2], nstd, tz);
            }
            tgt[k] = make_float4(tx, ty, tz, fmaf(tx,tx,fmaf(ty,ty,tz*tz)));
        }
        __syncthreads();
        #pragma unroll 8
        for (int k = 0; k < TM; ++k) {
            const float4 t = tgt[k];
            const float d2 = fmaf(m2x, t.x, fmaf(m2y, t.y, fmaf(m2z, t.z, t.w)));
            if (d2 < best) { best = d2; bestm = mt + k; }
        }
    }
    const size_t oc = ((size_t)b*MM + bestm)*3;
    float tx = clean[oc+0]-sx, ty = clean[oc+1]-sy, tz = clean[oc+2]-sz;
    if (nt) {
        const size_t on = (((size_t)mod*BB + b)*MM + bestm)*3;
        tx = fmaf(noise[on+0], nstd, tx);
        ty = fmaf(noise[on+1], nstd, ty);
        tz = fmaf(noise[on+2], nstd, tz);
    }
    const float ex = dxp - (tx - qx), ey = dyp - (ty - qy), ez = dzp - (tz - qz);
    float v = fmaf(ex, ex, fmaf(ey, ey, ez*ez));
    for (int o = 32; o; o >>= 1) v += __shfl_down(v, o);
    if ((tid & 63) == 0) red[tid >> 6] = v;
    __syncthreads();
    if (tid == 0)
        partials[(((size_t)mod*BB + b)*NXBLK2) + blockIdx.x] = red[0]+red[1]+red[2]+red[3];
}

extern "C" void kernel_launch(void* const* d_in, const int* in_sizes, int n_in,
                              void* d_out, int out_size, void* d_ws, size_t ws_size,
                              hipStream_t stream) {
    const float* noisy = (const float*)d_in[0];
    const float* clean = (const float*)d_in[1];
    const float* seeds = (const float*)d_in[2];
    const float* stds  = (const float*)d_in[3];
    const float* disp  = (const float*)d_in[4];
    const float* noise = (const float*)d_in[5];
    float* out = (float*)d_out;

    if (ws_size >= WS_TIER(16)) {
        char* base = (char*)d_ws;
        float4* tbl = (float4*)base;
        unsigned long long* keys = (unsigned long long*)(base + OFF_KEYS);

        dim3 gb(MM / TPB, NG);
        build_tbl<<<gb, TPB, 0, stream>>>(clean, seeds, stds, noise, tbl);

        if (ws_size >= WS_TIER(32)) {
            float* partials = (float*)(base + OFF_KEYS + KEYB(32));
            dim3 g1(NXB, BB, NMOD * 32);
            nn_min_kernel<32><<<g1, TPB, 0, stream>>>(noisy, seeds, disp, tbl, keys);
            dim3 g2(NXBLK2, BB, NMOD);
            nn_loss_pass2<32><<<g2, TPB, 0, stream>>>(noisy, seeds, disp, tbl, keys, partials);
            finalize_kernel<<<1, 64, 0, stream>>>(partials, out);
        } else {
            float* partials = (float*)(base + OFF_KEYS + KEYB(16));
            dim3 g1(NXB, BB, NMOD * 16);
            nn_min_kernel<16><<<g1, TPB, 0, stream>>>(noisy, seeds, disp, tbl, keys);
            dim3 g2(NXBLK2, BB, NMOD);
            nn_loss_pass2<16><<<g2, TPB, 0, stream>>>(noisy, seeds, disp, tbl, keys, partials);
            finalize_kernel<<<1, 64, 0, stream>>>(partials, out);
        }
    } else {
        float* partials = (float*)d_ws;
        dim3 grid(NXBLK2, BB, NMOD);
        nn_loss_kernel<<<grid, TPB, 0, stream>>>(noisy, clean, seeds, stds,
                                                 disp, noise, partials);
        finalize_kernel<<<1, 64, 0, stream>>>(partials, out);
    }
}

// Round 15
// 75.172 us; speedup vs baseline: 184.2995x; 2.0735x over previous
//
#include <hip/hip_runtime.h>
#include <math.h>

#define NMOD 4
#define BB   8
#define NN   4096
#define MM   4608
#define TPB  256

// ---- fast path geometry ----
#define QPT      8                      // queries per thread (named scalars)
#define QPB      (TPB * QPT)            // 2048 queries per block
#define NXB      (NN / QPB)             // 2
#define SLICES   16
#define SLICE_M  (MM / SLICES)          // 288
#define CH       16                     // targets per chunk
#define CHP      (CH + 1)               // padded chunk stride (bank aliasing)
#define NCHUNK   (SLICE_M / CH)         // 18
#define NSUP     (NCHUNK / 3)           // 6 superchunks (3 chunks = 24 pairs)
#define TOTP     (SLICE_M / 2)          // 144 pairs
#define QCOUNT   (NMOD * BB * NN)       // 131072
#define NXBLK2   (NN / TPB)             // 16
#define NPART    (NMOD * BB * NXBLK2)   // 512
#define KEYB     ((size_t)SLICES * QCOUNT * 8)   // 16.78 MB
#define WS_NEED  (KEYB + (size_t)NPART * 4)

static __device__ __forceinline__ float min3f(float a, float b, float c) {
    float d;
    asm("v_min3_f32 %0, %1, %2, %3" : "=v"(d) : "v"(a), "v"(b), "v"(c));
    return d;
}

// identical FMA chain in scan and rescan -> bit-exact equality
#define CHAIN(T, MX, MY, MZ) \
    fmaf(MX, (T).x, fmaf(MY, (T).y, fmaf(MZ, (T).z, (T).w)))

// ---------------- pass 1: software-pipelined chunked min3 argmin ------------
// 3-slot rotating pair buffers (A,B,C): step k evaluates the pair loaded at
// step k-3 and prefetches pair k+3 into the freed slot -> ds_read latency
// (~120cy) hidden under ~220cy of VALU. All buffer names static (rule #20).
__global__ __launch_bounds__(TPB, 4) void nn_min_kernel(
    const float* __restrict__ noisy, const float* __restrict__ clean,
    const float* __restrict__ seeds, const float* __restrict__ stds,
    const float* __restrict__ disp,  const float* __restrict__ noise,
    unsigned long long* __restrict__ keys)
{
    __shared__ float4 TS[NCHUNK][CHP];

    const int tid   = threadIdx.x;
    const int b     = blockIdx.y;
    const int mod   = blockIdx.z >> 4;
    const int sl    = blockIdx.z & 15;
    const int mbase = sl * SLICE_M;
    const int nb    = blockIdx.x * QPB + tid;

    const float sx = seeds[b * 3 + 0];
    const float sy = seeds[b * 3 + 1];
    const float sz = seeds[b * 3 + 2];
    float nstd = 0.0f;
    if (mod == 0) nstd = stds[b] * 0.25f;
    else if (mod == 1) nstd = stds[b] * 0.0625f;
    const bool nt = (mod < 2);

    // stage this 288-target slice
    for (int k = tid; k < SLICE_M; k += TPB) {
        const int m = mbase + k;
        const size_t oc = ((size_t)b * MM + m) * 3;
        float tx = clean[oc + 0] - sx;
        float ty = clean[oc + 1] - sy;
        float tz = clean[oc + 2] - sz;
        if (nt) {
            const size_t on = (((size_t)mod * BB + b) * MM + m) * 3;
            tx = fmaf(noise[on + 0], nstd, tx);
            ty = fmaf(noise[on + 1], nstd, ty);
            tz = fmaf(noise[on + 2], nstd, tz);
        }
        const float tw = fmaf(tx, tx, fmaf(ty, ty, tz * tz));
        TS[k >> 4][k & 15] = make_float4(tx, ty, tz, tw);
    }

    // ---- 8 queries, named scalars only ----
    float m2x0, m2y0, m2z0, m2x1, m2y1, m2z1, m2x2, m2y2, m2z2, m2x3, m2y3, m2z3;
    float m2x4, m2y4, m2z4, m2x5, m2y5, m2z5, m2x6, m2y6, m2z6, m2x7, m2y7, m2z7;

#define QSETUP(K, MX, MY, MZ) do {                                        \
        const int n = nb + (K) * TPB;                                     \
        const size_t o0 = ((size_t)b * NN + n) * 3;                       \
        float qx = noisy[o0 + 0] - sx;                                    \
        float qy = noisy[o0 + 1] - sy;                                    \
        float qz = noisy[o0 + 2] - sz;                                    \
        for (int j = 0; j < mod; ++j) {                                   \
            const size_t o = (((size_t)j * BB + b) * NN + n) * 3;         \
            qx += disp[o + 0]; qy += disp[o + 1]; qz += disp[o + 2];      \
        }                                                                 \
        MX = -2.0f * qx; MY = -2.0f * qy; MZ = -2.0f * qz;                \
    } while (0)

    QSETUP(0, m2x0, m2y0, m2z0); QSETUP(1, m2x1, m2y1, m2z1);
    QSETUP(2, m2x2, m2y2, m2z2); QSETUP(3, m2x3, m2y3, m2z3);
    QSETUP(4, m2x4, m2y4, m2z4); QSETUP(5, m2x5, m2y5, m2z5);
    QSETUP(6, m2x6, m2y6, m2z6); QSETUP(7, m2x7, m2y7, m2z7);
#undef QSETUP

    __syncthreads();

    float bb0 = INFINITY, bb1 = INFINITY, bb2 = INFINITY, bb3 = INFINITY;
    float bb4 = INFINITY, bb5 = INFINITY, bb6 = INFINITY, bb7 = INFINITY;
    int cc0 = 0, cc1 = 0, cc2 = 0, cc3 = 0, cc4 = 0, cc5 = 0, cc6 = 0, cc7 = 0;

    // 3-slot pipeline buffers
    float4 A0 = TS[0][0], A1 = TS[0][1];
    float4 B0 = TS[0][2], B1 = TS[0][3];
    float4 C0 = TS[0][4], C1 = TS[0][5];

#define EVAL2_(T0, T1, MX, MY, MZ, A) do {                                \
        const float d0_ = CHAIN(T0, MX, MY, MZ);                          \
        const float d1_ = CHAIN(T1, MX, MY, MZ);                          \
        A = min3f(d0_, d1_, A);                                           \
    } while (0)

#define EVAL8(T0, T1) do {                                                \
        EVAL2_(T0, T1, m2x0, m2y0, m2z0, a0);                             \
        EVAL2_(T0, T1, m2x1, m2y1, m2z1, a1);                             \
        EVAL2_(T0, T1, m2x2, m2y2, m2z2, a2);                             \
        EVAL2_(T0, T1, m2x3, m2y3, m2z3, a3);                             \
        EVAL2_(T0, T1, m2x4, m2y4, m2z4, a4);                             \
        EVAL2_(T0, T1, m2x5, m2y5, m2z5, a5);                             \
        EVAL2_(T0, T1, m2x6, m2y6, m2z6, a6);                             \
        EVAL2_(T0, T1, m2x7, m2y7, m2z7, a7);                             \
    } while (0)

#define PREF(S0, S1, PIDX) do {                                           \
        int pp_ = (PIDX); pp_ = pp_ < TOTP ? pp_ : TOTP - 1;              \
        S0 = TS[pp_ >> 3][(pp_ & 7) * 2];                                 \
        S1 = TS[pp_ >> 3][(pp_ & 7) * 2 + 1];                             \
    } while (0)

#define STEP(S0, S1, PIDX) do { EVAL8(S0, S1); PREF(S0, S1, PIDX); } while (0)

#define RESETA() do { a0 = a1 = a2 = a3 = a4 = a5 = a6 = a7 = INFINITY; } while (0)

#define CUPD1(A, BV, CV, CI) do {                                         \
        const bool c_ = (A) < (BV);                                       \
        BV = c_ ? (A) : (BV);                                             \
        CV = c_ ? (CI) : (CV);                                            \
    } while (0)

#define CUPD8(CI) do {                                                    \
        const int ci_ = (CI);                                             \
        CUPD1(a0, bb0, cc0, ci_); CUPD1(a1, bb1, cc1, ci_);               \
        CUPD1(a2, bb2, cc2, ci_); CUPD1(a3, bb3, cc3, ci_);               \
        CUPD1(a4, bb4, cc4, ci_); CUPD1(a5, bb5, cc5, ci_);               \
        CUPD1(a6, bb6, cc6, ci_); CUPD1(a7, bb7, cc7, ci_);               \
    } while (0)

    int pb = 0;
    #pragma unroll 1
    for (int sc = 0; sc < NSUP; ++sc) {
        float a0, a1, a2, a3, a4, a5, a6, a7;
        // chunk 3sc+0: local pairs 0..7, slots 0,1,2,0,1,2,0,1
        RESETA();
        STEP(A0, A1, pb + 3);  STEP(B0, B1, pb + 4);  STEP(C0, C1, pb + 5);
        STEP(A0, A1, pb + 6);  STEP(B0, B1, pb + 7);  STEP(C0, C1, pb + 8);
        STEP(A0, A1, pb + 9);  STEP(B0, B1, pb + 10);
        CUPD8(3 * sc);
        // chunk 3sc+1: local pairs 8..15, slots 2,0,1,2,0,1,2,0
        RESETA();
        STEP(C0, C1, pb + 11); STEP(A0, A1, pb + 12); STEP(B0, B1, pb + 13);
        STEP(C0, C1, pb + 14); STEP(A0, A1, pb + 15); STEP(B0, B1, pb + 16);
        STEP(C0, C1, pb + 17); STEP(A0, A1, pb + 18);
        CUPD8(3 * sc + 1);
        // chunk 3sc+2: local pairs 16..23, slots 1,2,0,1,2,0,1,2
        RESETA();
        STEP(B0, B1, pb + 19); STEP(C0, C1, pb + 20); STEP(A0, A1, pb + 21);
        STEP(B0, B1, pb + 22); STEP(C0, C1, pb + 23); STEP(A0, A1, pb + 24);
        STEP(B0, B1, pb + 25); STEP(C0, C1, pb + 26);
        CUPD8(3 * sc + 2);
        pb += 24;
    }

    unsigned long long* __restrict__ kslice = keys + (size_t)sl * QCOUNT
                                            + (((size_t)mod * BB + b) * NN);

    // rescan winning chunk (backward overwrite -> first match), pack, store
#define FINQ(K, MX, MY, MZ, BV, CV) do {                                  \
        int im = 0;                                                       \
        for (int u = CH - 1; u >= 0; --u) {                               \
            const float4 t = TS[CV][u];                                   \
            const float d = CHAIN(t, MX, MY, MZ);                         \
            im = (d == (BV)) ? ((CV) * CH + u) : im;                      \
        }                                                                 \
        const float q2 = 0.25f * fmaf(MX, MX, fmaf(MY, MY, (MZ) * (MZ)));\
        const float f = (BV) + q2 + 8.0f;                                 \
        const unsigned long long key =                                    \
            ((unsigned long long)__float_as_uint(f) << 32) |              \
            (unsigned int)(mbase + im);                                   \
        kslice[nb + (K) * TPB] = key;                                     \
    } while (0)

    FINQ(0, m2x0, m2y0, m2z0, bb0, cc0);
    FINQ(1, m2x1, m2y1, m2z1, bb1, cc1);
    FINQ(2, m2x2, m2y2, m2z2, bb2, cc2);
    FINQ(3, m2x3, m2y3, m2z3, bb3, cc3);
    FINQ(4, m2x4, m2y4, m2z4, bb4, cc4);
    FINQ(5, m2x5, m2y5, m2z5, bb5, cc5);
    FINQ(6, m2x6, m2y6, m2z6, bb6, cc6);
    FINQ(7, m2x7, m2y7, m2z7, bb7, cc7);
#undef FINQ
}

// ---------------- pass 2: combine slices, unpack winner, loss ---------------
__global__ __launch_bounds__(TPB) void nn_loss_pass2(
    const float* __restrict__ noisy, const float* __restrict__ clean,
    const float* __restrict__ seeds, const float* __restrict__ stds,
    const float* __restrict__ disp,  const float* __restrict__ noise,
    const unsigned long long* __restrict__ keys,
    float* __restrict__ partials)
{
    __shared__ float red[TPB / 64];
    const int tid = threadIdx.x;
    const int b   = blockIdx.y;
    const int mod = blockIdx.z;
    const int n   = blockIdx.x * TPB + tid;

    const float sx = seeds[b * 3 + 0];
    const float sy = seeds[b * 3 + 1];
    const float sz = seeds[b * 3 + 2];
    float nstd = 0.0f;
    if (mod == 0) nstd = stds[b] * 0.25f;
    else if (mod == 1) nstd = stds[b] * 0.0625f;

    float qx = noisy[((size_t)b * NN + n) * 3 + 0] - sx;
    float qy = noisy[((size_t)b * NN + n) * 3 + 1] - sy;
    float qz = noisy[((size_t)b * NN + n) * 3 + 2] - sz;
    for (int j = 0; j < mod; ++j) {
        const size_t o = (((size_t)j * BB + b) * NN + n) * 3;
        qx += disp[o + 0]; qy += disp[o + 1]; qz += disp[o + 2];
    }
    const size_t od = (((size_t)mod * BB + b) * NN + n) * 3;
    const float dxp = disp[od + 0];
    const float dyp = disp[od + 1];
    const float dzp = disp[od + 2];

    const size_t q = (((size_t)mod * BB + b) * NN) + n;
    unsigned long long k = keys[q];
    #pragma unroll
    for (int s = 1; s < SLICES; ++s) {
        const unsigned long long v = keys[(size_t)s * QCOUNT + q];
        k = v < k ? v : k;
    }
    const unsigned gidx = (unsigned)(k & 0xFFFFFFFFull);

    const size_t oc = ((size_t)b * MM + gidx) * 3;
    float tx = clean[oc + 0] - sx;
    float ty = clean[oc + 1] - sy;
    float tz = clean[oc + 2] - sz;
    if (mod < 2) {
        const size_t on = (((size_t)mod * BB + b) * MM + gidx) * 3;
        tx = fmaf(noise[on + 0], nstd, tx);
        ty = fmaf(noise[on + 1], nstd, ty);
        tz = fmaf(noise[on + 2], nstd, tz);
    }
    const float ex = dxp - (tx - qx);
    const float ey = dyp - (ty - qy);
    const float ez = dzp - (tz - qz);
    float v = fmaf(ex, ex, fmaf(ey, ey, ez * ez));

    for (int o = 32; o; o >>= 1) v += __shfl_down(v, o);
    if ((tid & 63) == 0) red[tid >> 6] = v;
    __syncthreads();
    if (tid == 0) {
        const float s = red[0] + red[1] + red[2] + red[3];
        partials[(((size_t)mod * BB + b) * NXBLK2) + blockIdx.x] = s;
    }
}

__global__ void finalize_kernel(const float* __restrict__ partials, float* __restrict__ out) {
    float s = 0.0f;
    for (int k = threadIdx.x; k < NPART; k += 64) s += partials[k];
    for (int o = 32; o; o >>= 1) s += __shfl_down(s, o);
    if (threadIdx.x == 0) {
        out[0] = s * (1.0f / BB);
        out[1] = s * (1.0f / BB);
    }
}

// ---------------- monolithic dense fallback (2 KiB ws) ----------------------
#define TM 768
__global__ __launch_bounds__(TPB) void nn_loss_kernel(
    const float* __restrict__ noisy, const float* __restrict__ clean,
    const float* __restrict__ seeds, const float* __restrict__ stds,
    const float* __restrict__ disp,  const float* __restrict__ noise,
    float* __restrict__ partials)
{
    __shared__ float4 tgt[TM];
    __shared__ float red[TPB / 64];
    const int tid = threadIdx.x;
    const int b = blockIdx.y, mod = blockIdx.z;
    const int n = blockIdx.x * TPB + tid;
    const float sx = seeds[b*3+0], sy = seeds[b*3+1], sz = seeds[b*3+2];
    float qx = noisy[((size_t)b*NN+n)*3+0] - sx;
    float qy = noisy[((size_t)b*NN+n)*3+1] - sy;
    float qz = noisy[((size_t)b*NN+n)*3+2] - sz;
    for (int j = 0; j < mod; ++j) {
        const size_t o = (((size_t)j*BB + b)*NN + n)*3;
        qx += disp[o+0]; qy += disp[o+1]; qz += disp[o+2];
    }
    const size_t od = (((size_t)mod*BB + b)*NN + n)*3;
    const float dxp = disp[od+0], dyp = disp[od+1], dzp = disp[od+2];
    float nstd = 0.0f;
    if (mod == 0) nstd = stds[b]*0.25f; else if (mod == 1) nstd = stds[b]*0.0625f;
    const bool nt = (mod < 2);
    const float m2x = -2.0f*qx, m2y = -2.0f*qy, m2z = -2.0f*qz;
    float best = INFINITY; int bestm = 0;
    for (int mt = 0; mt < MM; mt += TM) {
        __syncthreads();
        for (int k = tid; k < TM; k += TPB) {
            const int m = mt + k;
            const size_t oc = ((size_t)b*MM + m)*3;
            float tx = clean[oc+0]-sx, ty = clean[oc+1]-sy, tz = clean[oc+2]-sz;
            if (nt) {
                const size_t on = (((size_t)mod*BB + b)*MM + m)*3;
                tx = fmaf(noise[on+0], nstd, tx);
                ty = fmaf(noise[on+1], nstd, ty);
                tz = fmaf(noise[on+2], nstd, tz);
            }
            tgt[k] = make_float4(tx, ty, tz, fmaf(tx,tx,fmaf(ty,ty,tz*tz)));
        }
        __syncthreads();
        #pragma unroll 8
        for (int k = 0; k < TM; ++k) {
            const float4 t = tgt[k];
            const float d2 = fmaf(m2x, t.x, fmaf(m2y, t.y, fmaf(m2z, t.z, t.w)));
            if (d2 < best) { best = d2; bestm = mt + k; }
        }
    }
    const size_t oc = ((size_t)b*MM + bestm)*3;
    float tx = clean[oc+0]-sx, ty = clean[oc+1]-sy, tz = clean[oc+2]-sz;
    if (nt) {
        const size_t on = (((size_t)mod*BB + b)*MM + bestm)*3;
        tx = fmaf(noise[on+0], nstd, tx);
        ty = fmaf(noise[on+1], nstd, ty);
        tz = fmaf(noise[on+2], nstd, tz);
    }
    const float ex = dxp - (tx - qx), ey = dyp - (ty - qy), ez = dzp - (tz - qz);
    float v = fmaf(ex, ex, fmaf(ey, ey, ez*ez));
    for (int o = 32; o; o >>= 1) v += __shfl_down(v, o);
    if ((tid & 63) == 0) red[tid >> 6] = v;
    __syncthreads();
    if (tid == 0)
        partials[(((size_t)mod*BB + b)*NXBLK2) + blockIdx.x] = red[0]+red[1]+red[2]+red[3];
}

extern "C" void kernel_launch(void* const* d_in, const int* in_sizes, int n_in,
                              void* d_out, int out_size, void* d_ws, size_t ws_size,
                              hipStream_t stream) {
    const float* noisy = (const float*)d_in[0];
    const float* clean = (const float*)d_in[1];
    const float* seeds = (const float*)d_in[2];
    const float* stds  = (const float*)d_in[3];
    const float* disp  = (const float*)d_in[4];
    const float* noise = (const float*)d_in[5];
    float* out = (float*)d_out;

    if (ws_size >= WS_NEED) {
        unsigned long long* keys = (unsigned long long*)d_ws;
        float* partials = (float*)((char*)d_ws + KEYB);
        dim3 g1(NXB, BB, NMOD * SLICES);
        nn_min_kernel<<<g1, TPB, 0, stream>>>(noisy, clean, seeds, stds, disp, noise, keys);
        dim3 g2(NXBLK2, BB, NMOD);
        nn_loss_pass2<<<g2, TPB, 0, stream>>>(noisy, clean, seeds, stds, disp, noise, keys, partials);
        finalize_kernel<<<1, 64, 0, stream>>>(partials, out);
    } else {
        float* partials = (float*)d_ws;
        dim3 grid(NXBLK2, BB, NMOD);
        nn_loss_kernel<<<grid, TPB, 0, stream>>>(noisy, clean, seeds, stds, disp, noise, partials);
        finalize_kernel<<<1, 64, 0, stream>>>(partials, out);
    }
}